// Round 3
// baseline (1006.685 us; speedup 1.0000x reference)
//
#include <hip/hip_runtime.h>

typedef _Float16 f16;
typedef _Float16 h4 __attribute__((ext_vector_type(4)));
typedef _Float16 v8h __attribute__((ext_vector_type(8)));
typedef _Float16 h8 __attribute__((ext_vector_type(8)));
typedef float v4f __attribute__((ext_vector_type(4)));

#define INV_SQRT_C 0.08838834764831845f

__device__ inline v8h zero8() {
  v8h v;
  #pragma unroll
  for (int k = 0; k < 8; k++) v[k] = (f16)0.f;
  return v;
}

// ---------------- conv1: 3->32, stride 1, 256x256, ReLU, NHWC fp16 out ----------------
__global__ __launch_bounds__(256) void conv1_k(const float* __restrict__ img,
    const float* __restrict__ w1, const float* __restrict__ b1, f16* __restrict__ out)
{
  const int h = blockIdx.x, b = blockIdx.y;
  const int w = threadIdx.x;
  __shared__ float sIn[3][3][258];
  const float* imgb = img + (long)b * 3 * 65536;
  for (int idx = threadIdx.x; idx < 3 * 3 * 258; idx += 256) {
    int col = idx % 258; int t2 = idx / 258; int r = t2 % 3; int c = t2 / 3;
    int ih = h - 1 + r, iw = col - 1;
    float v = 0.f;
    if (ih >= 0 && ih < 256 && iw >= 0 && iw < 256) v = imgb[c * 65536 + ih * 256 + iw];
    sIn[c][r][col] = v;
  }
  __syncthreads();
  float acc[32];
  #pragma unroll
  for (int u = 0; u < 32; u++) acc[u] = b1[u];
  for (int c = 0; c < 3; c++)
    #pragma unroll
    for (int kh = 0; kh < 3; kh++)
      #pragma unroll
      for (int kw = 0; kw < 3; kw++) {
        float v = sIn[c][kh][w + kw];
        #pragma unroll
        for (int u = 0; u < 32; u++) acc[u] = fmaf(v, w1[(u * 3 + c) * 9 + kh * 3 + kw], acc[u]);
      }
  h8* o8 = (h8*)(out + (((long)(b * 256 + h) * 256) + w) * 32);
  #pragma unroll
  for (int v8 = 0; v8 < 4; v8++) {
    h8 pk;
    #pragma unroll
    for (int k = 0; k < 8; k++) {
      float r = acc[v8 * 8 + k];
      pk[k] = (f16)(r > 0.f ? r : 0.f);
    }
    o8[v8] = pk;
  }
}

// ---------------- weight transforms: OIHW fp32 -> [khkw][oc][ic] fp16 ----------------
__global__ void wt2_k(const float* __restrict__ w2, f16* __restrict__ wT)
{
  int idx = blockIdx.x * 256 + threadIdx.x;          // 18432
  int ic = idx & 31, oc = (idx >> 5) & 63, khkw = idx >> 11;
  wT[idx] = (f16)w2[(oc * 32 + ic) * 9 + khkw];
}

__global__ void wt3_k(const float* __restrict__ w3, f16* __restrict__ wT)
{
  int idx = blockIdx.x * 256 + threadIdx.x;          // 73728
  int ic5 = idx & 31, oc = (idx >> 5) & 127, ch = idx >> 12;
  int khkw = ch >> 1, ich = ch & 1;
  int ic = ich * 32 + ic5;
  wT[idx] = (f16)w3[(oc * 64 + ic) * 9 + khkw];
}

// ---------------- conv2 MFMA: 32->64, stride 2, out 128x128, NHWC fp16 ----------------
// All 18 B-fragments prefetched before the MFMA loop (latency front-loaded).
__global__ __launch_bounds__(256) void conv2_m(const f16* __restrict__ in,
    const f16* __restrict__ wT, const float* __restrict__ b2, f16* __restrict__ out)
{
  const int oh = blockIdx.x, b = blockIdx.y;
  const int lane = threadIdx.x & 63, wv = threadIdx.x >> 6;
  const int n15 = lane & 15, quad = lane >> 4;
  const int ow0 = wv * 32;
  v8h bf[3][3][2];
  #pragma unroll
  for (int kh = 0; kh < 3; kh++) {
    int ih = 2 * oh - 1 + kh;
    bool ihok = (unsigned)ih < 256u;
    const f16* rowb = in + ((long)(b * 256 + (ihok ? ih : 0))) * 8192;
    #pragma unroll
    for (int kw = 0; kw < 3; kw++)
      #pragma unroll
      for (int nt = 0; nt < 2; nt++) {
        int iw = 2 * (ow0 + nt * 16 + n15) + kw - 1;
        v8h v = zero8();
        if (ihok && (unsigned)iw < 256u) v = *(const v8h*)(rowb + iw * 32 + quad * 8);
        bf[kh][kw][nt] = v;
      }
  }
  v4f acc[4][2] = {};
  #pragma unroll
  for (int kh = 0; kh < 3; kh++)
    #pragma unroll
    for (int kw = 0; kw < 3; kw++) {
      const f16* wp = wT + (kh * 3 + kw) * 2048 + n15 * 32 + quad * 8;
      v8h a0 = *(const v8h*)(wp);
      v8h a1 = *(const v8h*)(wp + 512);
      v8h a2 = *(const v8h*)(wp + 1024);
      v8h a3 = *(const v8h*)(wp + 1536);
      v8h b0 = bf[kh][kw][0], b1 = bf[kh][kw][1];
      acc[0][0] = __builtin_amdgcn_mfma_f32_16x16x32_f16(a0, b0, acc[0][0], 0, 0, 0);
      acc[0][1] = __builtin_amdgcn_mfma_f32_16x16x32_f16(a0, b1, acc[0][1], 0, 0, 0);
      acc[1][0] = __builtin_amdgcn_mfma_f32_16x16x32_f16(a1, b0, acc[1][0], 0, 0, 0);
      acc[1][1] = __builtin_amdgcn_mfma_f32_16x16x32_f16(a1, b1, acc[1][1], 0, 0, 0);
      acc[2][0] = __builtin_amdgcn_mfma_f32_16x16x32_f16(a2, b0, acc[2][0], 0, 0, 0);
      acc[2][1] = __builtin_amdgcn_mfma_f32_16x16x32_f16(a2, b1, acc[2][1], 0, 0, 0);
      acc[3][0] = __builtin_amdgcn_mfma_f32_16x16x32_f16(a3, b0, acc[3][0], 0, 0, 0);
      acc[3][1] = __builtin_amdgcn_mfma_f32_16x16x32_f16(a3, b1, acc[3][1], 0, 0, 0);
    }
  #pragma unroll
  for (int mt = 0; mt < 4; mt++) {
    int oc0 = mt * 16 + quad * 4;
    float4 bb = *(const float4*)(b2 + oc0);
    #pragma unroll
    for (int nt = 0; nt < 2; nt++) {
      int ow = ow0 + nt * 16 + n15;
      h4 pk;
      #pragma unroll
      for (int r = 0; r < 4; r++) {
        float v = acc[mt][nt][r] + ((const float*)&bb)[r];
        pk[r] = (f16)(v > 0.f ? v : 0.f);
      }
      *(h4*)(out + (((long)(b * 128 + oh) * 128 + ow) * 64) + oc0) = pk;
    }
  }
}

// ---------------- conv3 MFMA: 64->128, stride 2, out 64x64 ----------------
__global__ __launch_bounds__(256) void conv3_m(const f16* __restrict__ in,
    const f16* __restrict__ wT, const float* __restrict__ b3,
    float* __restrict__ zout, f16* __restrict__ nhwc)
{
  const int oh = blockIdx.x, b = blockIdx.y, ocg = blockIdx.z;
  const int lane = threadIdx.x & 63, wv = threadIdx.x >> 6;
  const int n15 = lane & 15, quad = lane >> 4;
  const int ow = wv * 16 + n15;
  v8h bf[3][3][2];  // kh, kw, ich
  #pragma unroll
  for (int kh = 0; kh < 3; kh++) {
    int ih = 2 * oh - 1 + kh;
    bool ihok = (unsigned)ih < 128u;
    const f16* rowb = in + ((long)(b * 128 + (ihok ? ih : 0))) * 8192;
    #pragma unroll
    for (int kw = 0; kw < 3; kw++) {
      int iw = 2 * ow + kw - 1;
      bool bok = ihok && (unsigned)iw < 128u;
      #pragma unroll
      for (int ich = 0; ich < 2; ich++) {
        v8h v = zero8();
        if (bok) v = *(const v8h*)(rowb + iw * 64 + ich * 32 + quad * 8);
        bf[kh][kw][ich] = v;
      }
    }
  }
  v4f acc[4] = {};
  #pragma unroll
  for (int ch = 0; ch < 18; ch++) {
    const f16* wp = wT + ((long)(ch * 128 + ocg * 64 + n15)) * 32 + quad * 8;
    v8h a0 = *(const v8h*)(wp);
    v8h a1 = *(const v8h*)(wp + 512);
    v8h a2 = *(const v8h*)(wp + 1024);
    v8h a3 = *(const v8h*)(wp + 1536);
    v8h bv = bf[ch / 6][(ch / 2) % 3][ch & 1];
    acc[0] = __builtin_amdgcn_mfma_f32_16x16x32_f16(a0, bv, acc[0], 0, 0, 0);
    acc[1] = __builtin_amdgcn_mfma_f32_16x16x32_f16(a1, bv, acc[1], 0, 0, 0);
    acc[2] = __builtin_amdgcn_mfma_f32_16x16x32_f16(a2, bv, acc[2], 0, 0, 0);
    acc[3] = __builtin_amdgcn_mfma_f32_16x16x32_f16(a3, bv, acc[3], 0, 0, 0);
  }
  #pragma unroll
  for (int mt = 0; mt < 4; mt++) {
    int oc0 = ocg * 64 + mt * 16 + quad * 4;
    float4 bb = *(const float4*)(b3 + oc0);
    float rv[4];
    #pragma unroll
    for (int r = 0; r < 4; r++) {
      float v = acc[mt][r] + ((const float*)&bb)[r];
      rv[r] = v > 0.f ? v : 0.f;
    }
    #pragma unroll
    for (int r = 0; r < 4; r++)
      zout[(((long)(b * 128 + oc0 + r) * 64 + oh) * 64) + ow] = rv[r];
    h4 pk;
    #pragma unroll
    for (int r = 0; r < 4; r++) pk[r] = (f16)rv[r];
    *(h4*)(nhwc + (((long)(b * 64 + oh) * 64 + ow) * 128) + oc0) = pk;
  }
}

// ---------------- local correlation via MFMA band-GEMM ----------------
// block = (h, b), 4 waves. Wave wv handles ki = wv, wv+4, ...
// S = T U^T restricted to the 10 16x16 tiles covering |w-w'|<=6;
// band scattered through a per-wave LDS slab (zeroed once), stored coalesced.
__global__ __launch_bounds__(256) void corr_m(const f16* __restrict__ zt,
    const f16* __restrict__ zt1, float* __restrict__ corr)
{
  const int h = blockIdx.x, b = blockIdx.y;
  __shared__ f16 sT[64 * 136];          // T row-padded: 272B stride
  __shared__ float sOut[4][13 * 68];    // per-wave band slab
  const int lane = threadIdx.x & 63, wv = threadIdx.x >> 6;
  const int n15 = lane & 15, quad = lane >> 4;

  const h8* tp = (const h8*)(zt + ((long)(b * 64 + h) * 64) * 128);
  for (int idx = threadIdx.x; idx < 1024; idx += 256) {
    int w = idx >> 4, c8 = idx & 15;
    *(h8*)(sT + w * 136 + c8 * 8) = tp[idx];
  }
  float* soall = &sOut[0][0];
  for (int i = threadIdx.x; i < 4 * 13 * 68; i += 256) soall[i] = 0.f;
  __syncthreads();

  volatile float* sO = &sOut[wv][0];
  float* cb = corr + (long)b * 169 * 4096 + h * 64;
  constexpr int TM[10] = {0, 0, 1, 1, 1, 2, 2, 2, 3, 3};
  constexpr int TN[10] = {0, 1, 0, 1, 2, 1, 2, 3, 2, 3};

  for (int ki = wv; ki < 13; ki += 4) {
    int row = h + ki - 6;
    if ((unsigned)row >= 64u) {
      for (int kj = 0; kj < 13; kj++)
        cb[(long)(ki * 13 + kj) * 4096 + lane] = 0.f;
      continue;
    }
    const f16* ub = zt1 + ((long)(b * 64 + row) * 64) * 128;
    v8h bfr[4][4];
    #pragma unroll
    for (int nt = 0; nt < 4; nt++)
      #pragma unroll
      for (int kk = 0; kk < 4; kk++)
        bfr[nt][kk] = *(const v8h*)(ub + (nt * 16 + n15) * 128 + kk * 32 + quad * 8);
    v4f acc[10] = {};
    #pragma unroll
    for (int kk = 0; kk < 4; kk++) {
      v8h af[4];
      #pragma unroll
      for (int mt = 0; mt < 4; mt++)
        af[mt] = *(const v8h*)(sT + (mt * 16 + n15) * 136 + kk * 32 + quad * 8);
      #pragma unroll
      for (int t = 0; t < 10; t++)
        acc[t] = __builtin_amdgcn_mfma_f32_16x16x32_f16(af[TM[t]], bfr[TN[t]][kk], acc[t], 0, 0, 0);
    }
    // scatter the band into the wave's LDS slab (D: row m = quad*4+r, col n = n15)
    #pragma unroll
    for (int t = 0; t < 10; t++) {
      int m0 = TM[t] * 16 + quad * 4;
      int n = TN[t] * 16 + n15;
      #pragma unroll
      for (int r = 0; r < 4; r++) {
        int m = m0 + r;
        int kj = n - m + 6;
        if ((unsigned)kj < 13u) sO[kj * 68 + m] = acc[t][r] * INV_SQRT_C;
      }
    }
    // coalesced store: 13 rows of 64 floats
    for (int kj = 0; kj < 13; kj++)
      cb[(long)(ki * 13 + kj) * 4096 + lane] = sO[kj * 68 + lane];
  }
}

// ---------------- h_t: mean over 64x64 per (b, offset) ----------------
__global__ __launch_bounds__(256) void ht_k(const float* __restrict__ corr, float* __restrict__ ht)
{
  const float4* p = (const float4*)(corr + (long)blockIdx.x * 4096);
  float s = 0.f;
  for (int i = threadIdx.x; i < 1024; i += 256) {
    float4 v = p[i];
    s += v.x + v.y + v.z + v.w;
  }
  #pragma unroll
  for (int off = 32; off > 0; off >>= 1) s += __shfl_down(s, off, 64);
  __shared__ float ps[4];
  if ((threadIdx.x & 63) == 0) ps[threadIdx.x >> 6] = s;
  __syncthreads();
  if (threadIdx.x == 0) ht[blockIdx.x] = (ps[0] + ps[1] + ps[2] + ps[3]) * (1.f / 4096.f);
}

// ---------------- pred: h_t @ w_head.T + b_head ----------------
__global__ void pred_k(const float* __restrict__ ht, const float* __restrict__ wh,
                       const float* __restrict__ bh, float* __restrict__ pred)
{
  int t = threadIdx.x;
  int b = t >> 1, j = t & 1;
  float s = bh[j];
  for (int o = 0; o < 169; o++) s = fmaf(ht[b * 169 + o], wh[j * 169 + o], s);
  pred[b * 2 + j] = s;
}

extern "C" void kernel_launch(void* const* d_in, const int* in_sizes, int n_in,
                              void* d_out, int out_size, void* d_ws, size_t ws_size,
                              hipStream_t stream)
{
  (void)in_sizes; (void)n_in; (void)out_size; (void)ws_size;
  const float* img_t  = (const float*)d_in[0];
  const float* img_t1 = (const float*)d_in[1];
  const float* w1 = (const float*)d_in[2];
  const float* b1 = (const float*)d_in[3];
  const float* w2 = (const float*)d_in[4];
  const float* b2 = (const float*)d_in[5];
  const float* w3 = (const float*)d_in[6];
  const float* b3 = (const float*)d_in[7];
  const float* wh = (const float*)d_in[8];
  const float* bh = (const float*)d_in[9];
  float* out = (float*)d_out;

  char* ws = (char*)d_ws;
  f16* bufA = (f16*)ws;                       // conv1 out NHWC: 128 MiB
  f16* bufB = (f16*)(ws + 134217728L);        // conv2 out NHWC:  64 MiB
  f16* nhT  = (f16*)(ws + 201326592L);        // z_t  NHWC fp16:  32 MiB
  f16* nhT1 = (f16*)(ws + 234881024L);        // z_t1 NHWC fp16:  32 MiB

  const long OUT_ZT   = 64;
  const long OUT_ZT1  = OUT_ZT + 16777216L;
  const long OUT_CORR = OUT_ZT1 + 16777216L;
  const long OUT_HT   = OUT_CORR + 22151168L;

  // transposed weights live in the (not-yet-written) corr region of d_out;
  // corr_m fully overwrites this region afterwards.
  f16* wT2 = (f16*)(out + OUT_CORR);          // 36 KiB
  f16* wT3 = wT2 + 18432;                     // 144 KiB

  wt2_k<<<72, 256, 0, stream>>>(w2, wT2);
  wt3_k<<<288, 256, 0, stream>>>(w3, wT3);

  for (int img = 0; img < 2; img++) {
    const float* src = img ? img_t1 : img_t;
    float* zdst = out + (img ? OUT_ZT1 : OUT_ZT);
    f16* nh = img ? nhT1 : nhT;
    conv1_k<<<dim3(256, 32), 256, 0, stream>>>(src, w1, b1, bufA);
    conv2_m<<<dim3(128, 32), 256, 0, stream>>>(bufA, wT2, b2, bufB);
    conv3_m<<<dim3(64, 32, 2), 256, 0, stream>>>(bufB, wT3, b3, zdst, nh);
  }
  corr_m<<<dim3(64, 32), 256, 0, stream>>>(nhT, nhT1, out + OUT_CORR);
  ht_k<<<5408, 256, 0, stream>>>(out + OUT_CORR, out + OUT_HT);
  pred_k<<<1, 64, 0, stream>>>(out + OUT_HT, wh, bh, out);
}